// Round 8
// baseline (106.775 us; speedup 1.0000x reference)
//
#include <hip/hip_runtime.h>
#include <math.h>

#define H 512
#define W 512
#define TBINS 180
#define RBINS 360
#define NPIX (H*W)
#define NCELL (TBINS*RBINS)

#define THETA_MIN (-1.5707963267948966f)
#define T_BIN ((float)(3.141592653589793 / 179.0))
#define R_MIN (-724.0773439350246f)
#define R_BIN ((float)(2.0 * 724.0773439350246 / 359.0))
#define THR_VAR 100.0f
#define WSIG 6.0f          // bucket window: sigma_r<=10 -> <=33 rho bins -> <=2 tiles

#define NT 6               // rho tiles (64 cols each)
#define KB 32              // k-blocks per tile -> 192 gemm blocks
#define BCAP 32768
#define MPAD 192           // theta rows padded to 12 m-tiles of 16
#define PADC 32            // counts padded 128 B apart
#define TCELL (TBINS*64)   // 11520 slab cells per block

#define NEA 193            // theta edges
#define NEB 65             // rho edges
#define EST 33             // edge-row stride (conflict-free)

typedef short v8s __attribute__((ext_vector_type(8)));
typedef float v4f __attribute__((ext_vector_type(4)));

__device__ __forceinline__ float phi_cdf(float z) {
    return 0.5f * erfcf(-0.70710678118654752f * z);
}
__device__ __forceinline__ unsigned short f2bf(float f) {   // RNE f32->bf16
    unsigned u = __float_as_uint(f);
    return (unsigned short)((u + 0x7FFF + ((u >> 16) & 1)) >> 16);
}
__device__ __forceinline__ float bf2f(unsigned short b) {
    return __uint_as_float(((unsigned)b) << 16);
}

struct PixParams { float theta, rho, var_theta, var_rho; };

// Faithful to reference incl. row_s quirk (residual uses img[clip(hi+dx), wi]).
__device__ __forceinline__ PixParams compute_pixel(const float* __restrict__ img,
                                                   int hi, int wi) {
    int xm = max(hi - 1, 0), xp = min(hi + 1, H - 1);
    int ym = max(wi - 1, 0), yp = min(wi + 1, W - 1);
    const float* r0 = img + xm * W;
    const float* r1 = img + hi * W;
    const float* r2 = img + xp * W;
    float s00 = r0[ym], s01 = r0[wi], s02 = r0[yp];
    float s10 = r1[ym], s11 = r1[wi], s12 = r1[yp];
    float s20 = r2[ym], s21 = r2[wi], s22 = r2[yp];

    float alpha_s = (s20 + s21 + s22) - (s00 + s01 + s02);
    float beta_s  = (s02 + s12 + s22) - (s00 + s10 + s20);
    float gsum    = s00 + s01 + s02 + s10 + s11 + s12 + s20 + s21 + s22;

    float alpha = alpha_s * (1.0f / 6.0f) + 1e-6f;
    float beta  = beta_s  * (1.0f / 6.0f) + 1e-6f;
    float gamma = gsum * (1.0f / 9.0f);

    float cvals[3] = { s01, s11, s21 };
    float eps2 = 0.0f;
    #pragma unroll
    for (int ix = 0; ix < 3; ++ix) {
        float dx = (float)(ix - 1);
        float c = cvals[ix];
        #pragma unroll
        for (int iy = 0; iy < 3; ++iy) {
            float dy = (float)(iy - 1);
            float r = c - alpha * dy - beta * dx - gamma;
            eps2 += r * r;
        }
    }
    float noise_var = eps2 * (1.0f / 7.0f);
    float va = noise_var * (1.0f / 6.0f);
    float g2 = alpha * alpha + beta * beta;
    float var_theta = (beta * beta * va + alpha * alpha * va) / (g2 * g2);

    float theta = atanf(beta / alpha);
    float ct = cosf(theta), st = sinf(theta);
    float x = (float)hi, y = (float)wi;
    float rho = x * ct + y * st;
    float drho = -x * st + y * ct;

    PixParams pp;
    pp.theta = theta; pp.rho = rho; pp.var_theta = var_theta;
    pp.var_rho = drho * drho * var_theta;
    return pp;
}

// Block-aggregated bucketing (R7 win): LDS histogram -> 1 global atomic per
// bucket per block. Records = 4 B pixel index.
__global__ void prep_kernel(const float* __restrict__ img,
                            const float* __restrict__ mask,
                            int* __restrict__ counts,
                            int* __restrict__ list) {
    __shared__ int lcnt[NT], gbase[NT];
    int tid = threadIdx.x;
    if (tid < NT) lcnt[tid] = 0;
    __syncthreads();

    int p = blockIdx.x * blockDim.x + tid;
    int hi = p >> 9, wi = p & (W - 1);
    float mv = mask[p];
    PixParams pp = compute_pixel(img, hi, wi);

    int myNt[2] = { -1, -1 };
    int myPos[2];
    bool valid = (pp.var_theta <= THR_VAR) && (pp.var_rho <= THR_VAR) && (mv != 0.0f);
    if (valid) {
        float sig_r = sqrtf(pp.var_rho + 1e-12f);
        float radr = WSIG * sig_r;
        int rlo = max((int)floorf((pp.rho - radr - R_MIN) / R_BIN - 0.5f), 0);
        int rhi = min((int)ceilf((pp.rho + radr - R_MIN) / R_BIN + 0.5f), RBINS - 1);
        if (rhi >= rlo) {
            int nt0 = rlo >> 6, nt1 = rhi >> 6;   // window <= 33 bins -> <= 2 tiles
            for (int nt = nt0; nt <= nt1; ++nt) {
                int k = nt - nt0;
                myNt[k] = nt;
                myPos[k] = atomicAdd(&lcnt[nt], 1);
            }
        }
    }
    __syncthreads();
    if (tid < NT) {
        int c = lcnt[tid];
        gbase[tid] = c ? atomicAdd(&counts[tid * PADC], c) : 0;
    }
    __syncthreads();
    #pragma unroll
    for (int k = 0; k < 2; ++k) {
        if (myNt[k] >= 0) {
            int pos = gbase[myNt[k]] + myPos[k];
            if (pos < BCAP) list[myNt[k] * BCAP + pos] = p;
        }
    }
}

// GEMM M=192(pad) N=64/tile K=bucket; drain = plain stores to private slab
// (NO atomics anywhere in this kernel).
__global__ void __launch_bounds__(512)
gemm_kernel(const float* __restrict__ img,
            const float* __restrict__ mask,
            const int* __restrict__ list,
            const int* __restrict__ counts,
            float* __restrict__ slabs) {
    __shared__ unsigned short Ah[MPAD * 32], Al[MPAD * 32]; // [m][k]
    __shared__ unsigned short Bh[64 * 32],  Bl[64 * 32];    // [n][k]
    __shared__ float EA[NEA * EST], EB[NEB * EST];          // edge CDFs [edge][pix]
    __shared__ float4 prec[2][32];
    __shared__ float  pmv[2][32];

    int nt = blockIdx.x % NT, kb = blockIdx.x / NT;
    int tid = threadIdx.x;
    int lane = tid & 63, wv = tid >> 6;
    int nsub = wv & 3, mhalf = wv >> 2;

    int cn = min(counts[nt * PADC], BCAP);
    int chunk = (cn + KB - 1) / KB;
    int k0 = kb * chunk, k1 = min(k0 + chunk, cn);

    v4f zero = {0.f, 0.f, 0.f, 0.f};
    v4f acc[6];
    #pragma unroll
    for (int i = 0; i < 6; ++i) acc[i] = zero;

    const int* lb = list + (size_t)nt * BCAP;
    int c0 = nt * 64;

    if (tid < 32) {
        int idx = k0 + tid;
        float4 rc; rc.x = 0.f; rc.y = 0.f; rc.z = 0.f; rc.w = 0.f;
        float mv = 0.f;
        if (idx < k1) {
            int p = lb[idx];
            PixParams pp = compute_pixel(img, p >> 9, p & (W - 1));
            mv = mask[p];
            rc.x = pp.theta; rc.y = 1.0f / sqrtf(pp.var_theta + 1e-12f);
            rc.z = pp.rho;   rc.w = 1.0f / sqrtf(pp.var_rho + 1e-12f);
        }
        prec[0][tid] = rc; pmv[0][tid] = mv;
    }

    int parity = 0;
    for (int ks = k0; ks < k1; ks += 32, parity ^= 1) {
        __syncthreads();
        if (tid < 32) {
            int idx = ks + 32 + tid;
            if (ks + 32 < k1) {
                float4 rc; rc.x = 0.f; rc.y = 0.f; rc.z = 0.f; rc.w = 0.f;
                float mv = 0.f;
                if (idx < k1) {
                    int p = lb[idx];
                    PixParams pp = compute_pixel(img, p >> 9, p & (W - 1));
                    mv = mask[p];
                    rc.x = pp.theta; rc.y = 1.0f / sqrtf(pp.var_theta + 1e-12f);
                    rc.z = pp.rho;   rc.w = 1.0f / sqrtf(pp.var_rho + 1e-12f);
                }
                prec[parity ^ 1][tid] = rc; pmv[parity ^ 1][tid] = mv;
            }
        } else {
            for (int i = tid - 32; i < (NEA + NEB) * 32; i += 480) {
                int e = i >> 5, pix = i & 31;
                float4 rc = prec[parity][pix];
                if (e < NEA) {
                    float edge = THETA_MIN + ((float)e - 0.5f) * T_BIN;
                    EA[e * EST + pix] = phi_cdf((edge - rc.x) * rc.y);
                } else {
                    int n = e - NEA;
                    float edge = R_MIN + ((float)(c0 + n) - 0.5f) * R_BIN;
                    EB[n * EST + pix] = phi_cdf((edge - rc.z) * rc.w);
                }
            }
        }
        __syncthreads();

        {
            int pix = tid & 31, srow = tid >> 5;
            #pragma unroll
            for (int i = 0; i < 16; ++i) {
                int slot = srow + 16 * i;
                if (slot < MPAD) {
                    float wt = (EA[(slot + 1) * EST + pix] - EA[slot * EST + pix])
                             * pmv[parity][pix];
                    unsigned short hb = f2bf(wt);
                    Ah[slot * 32 + pix] = hb;
                    Al[slot * 32 + pix] = f2bf(wt - bf2f(hb));
                } else {
                    int n = slot - MPAD;
                    float wr = EB[(n + 1) * EST + pix] - EB[n * EST + pix];
                    unsigned short hb = f2bf(wr);
                    Bh[n * 32 + pix] = hb;
                    Bl[n * 32 + pix] = f2bf(wr - bf2f(hb));
                }
            }
        }
        __syncthreads();

        int kq = (lane >> 4) * 8;
        int mr = lane & 15;
        v8s bh = *((__shared__ v8s*)&Bh[(nsub * 16 + mr) * 32 + kq]);
        v8s bl = *((__shared__ v8s*)&Bl[(nsub * 16 + mr) * 32 + kq]);
        #pragma unroll
        for (int mt = 0; mt < 6; ++mt) {
            int mbase = (mhalf * 6 + mt) * 16;
            v8s ah = *((__shared__ v8s*)&Ah[(mbase + mr) * 32 + kq]);
            v8s al = *((__shared__ v8s*)&Al[(mbase + mr) * 32 + kq]);
            acc[mt] = __builtin_amdgcn_mfma_f32_16x16x32_bf16(ah, bh, acc[mt], 0, 0, 0);
            acc[mt] = __builtin_amdgcn_mfma_f32_16x16x32_bf16(ah, bl, acc[mt], 0, 0, 0);
            acc[mt] = __builtin_amdgcn_mfma_f32_16x16x32_bf16(al, bh, acc[mt], 0, 0, 0);
        }
    }

    // drain: plain stores to this block's private slab [row*64+colt]
    // C/D layout: col=lane&15 (n), row=(lane>>4)*4+reg (m)  [verified R6/R7]
    float* slab = slabs + (size_t)blockIdx.x * TCELL;
    int colt = nsub * 16 + (lane & 15);
    int rq = (lane >> 4) * 4;
    #pragma unroll
    for (int mt = 0; mt < 6; ++mt) {
        int rbase = (mhalf * 6 + mt) * 16 + rq;
        #pragma unroll
        for (int r = 0; r < 4; ++r) {
            int row = rbase + r;
            if (row < TBINS) slab[row * 64 + colt] = acc[mt][r];
        }
    }
}

// Sum KB partial slabs per tile; write each out cell exactly once (no init
// kernel needed for d_out).
__global__ void reduce_kernel(const float* __restrict__ slabs,
                              float* __restrict__ out) {
    int i = blockIdx.x * blockDim.x + threadIdx.x;
    if (i >= NT * TCELL) return;
    int tile = i / TCELL, cell = i - tile * TCELL;
    int row = cell >> 6, colt = cell & 63;
    int gcol = tile * 64 + colt;
    if (gcol >= RBINS) return;
    const float* base = slabs + (size_t)tile * TCELL + cell;
    float s0 = 0.f, s1 = 0.f, s2 = 0.f, s3 = 0.f;
    #pragma unroll
    for (int kb = 0; kb < KB; kb += 4) {
        s0 += base[(size_t)(kb + 0) * NT * TCELL];
        s1 += base[(size_t)(kb + 1) * NT * TCELL];
        s2 += base[(size_t)(kb + 2) * NT * TCELL];
        s3 += base[(size_t)(kb + 3) * NT * TCELL];
    }
    out[row * RBINS + gcol] = (s0 + s1) + (s2 + s3);
}

extern "C" void kernel_launch(void* const* d_in, const int* in_sizes, int n_in,
                              void* d_out, int out_size, void* d_ws, size_t ws_size,
                              hipStream_t stream) {
    const float* img  = (const float*)d_in[0];
    const float* mask = (const float*)d_in[1];
    float* out = (float*)d_out;

    // ws: counts @0 (1 KB) ; list @1024 (768 KB) ; slabs @787456 (8.85 MB)
    char* ws = (char*)d_ws;
    int*   counts = (int*)ws;
    int*   list   = (int*)(ws + 1024);
    float* slabs  = (float*)(ws + 1024 + (size_t)NT * BCAP * 4);

    hipMemsetAsync(counts, 0, NT * PADC * sizeof(int), stream);
    prep_kernel<<<NPIX / 256, 256, 0, stream>>>(img, mask, counts, list);
    gemm_kernel<<<NT * KB, 512, 0, stream>>>(img, mask, list, counts, slabs);
    reduce_kernel<<<(NT * TCELL + 255) / 256, 256, 0, stream>>>(slabs, out);
}

// Round 9
// 99.238 us; speedup vs baseline: 1.0759x; 1.0759x over previous
//
#include <hip/hip_runtime.h>
#include <math.h>

#define H 512
#define W 512
#define TBINS 180
#define RBINS 360
#define NPIX (H*W)
#define NCELL (TBINS*RBINS)

#define THETA_MIN (-1.5707963267948966f)
#define T_BIN ((float)(3.141592653589793 / 179.0))
#define R_MIN (-724.0773439350246f)
#define R_BIN ((float)(2.0 * 724.0773439350246 / 359.0))
#define THR_VAR 100.0f
#define WSIG 6.0f          // window: tail mass < 2e-9, << 1.16e-2 budget (stable R4-R8)

#define NT 6               // rho tiles (64 cols each)
#define KB 80              // k-blocks per tile -> 480 gemm blocks (~240 active)
#define BCAP 32768
#define MPAD 192           // theta rows padded to 12 m-tiles of 16
#define PADC 32            // counts padded 128 B apart
#define TCELL (TBINS*64)   // 11520 slab cells per block

#define NEA 193            // theta edges
#define NEB 65             // rho edges
#define NET (NEA + NEB)    // 258 combined
#define EST 33             // edge-row stride (conflict-free)

typedef short v8s __attribute__((ext_vector_type(8)));
typedef float v4f __attribute__((ext_vector_type(4)));

__device__ __forceinline__ float phi_cdf(float z) {
    return 0.5f * erfcf(-0.70710678118654752f * z);
}
__device__ __forceinline__ unsigned short f2bf(float f) {   // RNE f32->bf16
    unsigned u = __float_as_uint(f);
    return (unsigned short)((u + 0x7FFF + ((u >> 16) & 1)) >> 16);
}
__device__ __forceinline__ float bf2f(unsigned short b) {
    return __uint_as_float(((unsigned)b) << 16);
}

struct PixParams { float theta, rho, var_theta, var_rho; };

// Faithful to reference incl. row_s quirk (residual uses img[clip(hi+dx), wi]).
__device__ __forceinline__ PixParams compute_pixel(const float* __restrict__ img,
                                                   int hi, int wi) {
    int xm = max(hi - 1, 0), xp = min(hi + 1, H - 1);
    int ym = max(wi - 1, 0), yp = min(wi + 1, W - 1);
    const float* r0 = img + xm * W;
    const float* r1 = img + hi * W;
    const float* r2 = img + xp * W;
    float s00 = r0[ym], s01 = r0[wi], s02 = r0[yp];
    float s10 = r1[ym], s11 = r1[wi], s12 = r1[yp];
    float s20 = r2[ym], s21 = r2[wi], s22 = r2[yp];

    float alpha_s = (s20 + s21 + s22) - (s00 + s01 + s02);
    float beta_s  = (s02 + s12 + s22) - (s00 + s10 + s20);
    float gsum    = s00 + s01 + s02 + s10 + s11 + s12 + s20 + s21 + s22;

    float alpha = alpha_s * (1.0f / 6.0f) + 1e-6f;
    float beta  = beta_s  * (1.0f / 6.0f) + 1e-6f;
    float gamma = gsum * (1.0f / 9.0f);

    float cvals[3] = { s01, s11, s21 };
    float eps2 = 0.0f;
    #pragma unroll
    for (int ix = 0; ix < 3; ++ix) {
        float dx = (float)(ix - 1);
        float c = cvals[ix];
        #pragma unroll
        for (int iy = 0; iy < 3; ++iy) {
            float dy = (float)(iy - 1);
            float r = c - alpha * dy - beta * dx - gamma;
            eps2 += r * r;
        }
    }
    float noise_var = eps2 * (1.0f / 7.0f);
    float va = noise_var * (1.0f / 6.0f);
    float g2 = alpha * alpha + beta * beta;
    float var_theta = (beta * beta * va + alpha * alpha * va) / (g2 * g2);

    float theta = atanf(beta / alpha);
    float ct = cosf(theta), st = sinf(theta);
    float x = (float)hi, y = (float)wi;
    float rho = x * ct + y * st;
    float drho = -x * st + y * ct;

    PixParams pp;
    pp.theta = theta; pp.rho = rho; pp.var_theta = var_theta;
    pp.var_rho = drho * drho * var_theta;
    return pp;
}

// Block-aggregated bucketing; stores precomputed params (removes the
// 9-load+atan chain from gemm's prefetch).
__global__ void prep_kernel(const float* __restrict__ img,
                            const float* __restrict__ mask,
                            int* __restrict__ counts,
                            float4* __restrict__ recs,
                            float* __restrict__ mvs) {
    __shared__ int lcnt[NT], gbase[NT];
    int tid = threadIdx.x;
    if (tid < NT) lcnt[tid] = 0;
    __syncthreads();

    int p = blockIdx.x * blockDim.x + tid;
    int hi = p >> 9, wi = p & (W - 1);
    float mv = mask[p];
    PixParams pp = compute_pixel(img, hi, wi);

    int myNt[2] = { -1, -1 };
    int myPos[2];
    float4 rc;
    bool valid = (pp.var_theta <= THR_VAR) && (pp.var_rho <= THR_VAR) && (mv != 0.0f);
    if (valid) {
        float sig_t = sqrtf(pp.var_theta + 1e-12f);
        float sig_r = sqrtf(pp.var_rho + 1e-12f);
        float radr = WSIG * sig_r;
        int rlo = max((int)floorf((pp.rho - radr - R_MIN) / R_BIN - 0.5f), 0);
        int rhi = min((int)ceilf((pp.rho + radr - R_MIN) / R_BIN + 0.5f), RBINS - 1);
        if (rhi >= rlo) {
            rc.x = pp.theta; rc.y = 1.0f / sig_t; rc.z = pp.rho; rc.w = 1.0f / sig_r;
            int nt0 = rlo >> 6, nt1 = rhi >> 6;   // window <= 32 bins -> <= 2 tiles
            for (int nt = nt0; nt <= nt1; ++nt) {
                int k = nt - nt0;
                myNt[k] = nt;
                myPos[k] = atomicAdd(&lcnt[nt], 1);
            }
        }
    }
    __syncthreads();
    if (tid < NT) {
        int c = lcnt[tid];
        gbase[tid] = c ? atomicAdd(&counts[tid * PADC], c) : 0;
    }
    __syncthreads();
    #pragma unroll
    for (int k = 0; k < 2; ++k) {
        if (myNt[k] >= 0) {
            int pos = gbase[myNt[k]] + myPos[k];
            if (pos < BCAP) {
                recs[myNt[k] * BCAP + pos] = rc;
                mvs[myNt[k] * BCAP + pos] = mv;
            }
        }
    }
}

// GEMM M=192(pad) N=64/tile K=bucket. Edge fill is windowed: erfcf only on
// ~48 in-window edges, step {0,1} elsewhere (erfcf saturation -> exact).
__global__ void __launch_bounds__(512)
gemm_kernel(const float4* __restrict__ recs,
            const float* __restrict__ mvs,
            const int* __restrict__ counts,
            float* __restrict__ slabs) {
    __shared__ unsigned short Ah[MPAD * 32], Al[MPAD * 32]; // [m][k]
    __shared__ unsigned short Bh[64 * 32],  Bl[64 * 32];    // [n][k]
    __shared__ float EA[NEA * EST], EB[NEB * EST];          // edge CDFs [edge][pix]
    __shared__ float4 prec[2][32];
    __shared__ float  pmv[2][32];
    __shared__ int4   pwin[2][32];                          // tlo,thi,blo,bhi

    int nt = blockIdx.x % NT, kb = blockIdx.x / NT;
    int tid = threadIdx.x;
    int lane = tid & 63, wv = tid >> 6;
    int nsub = wv & 3, mhalf = wv >> 2;
    int c0 = nt * 64;
    int nbmax = min(63, RBINS - 1 - c0);

    int cn = min(counts[nt * PADC], BCAP);
    int chunkPix = (cn + KB - 1) / KB;
    int k0 = kb * chunkPix, k1 = min(k0 + chunkPix, cn);

    v4f zero = {0.f, 0.f, 0.f, 0.f};
    v4f acc[6];
    #pragma unroll
    for (int i = 0; i < 6; ++i) acc[i] = zero;

    const float4* rb = recs + (size_t)nt * BCAP;
    const float*  mb = mvs + (size_t)nt * BCAP;

    // prefetch chunk 0 (params + windows)
    if (tid < 32) {
        int idx = k0 + tid;
        float4 rc; rc.x = 0.f; rc.y = 0.f; rc.z = 0.f; rc.w = 0.f;
        float mv = 0.f;
        int4 w; w.x = 0; w.y = -1; w.z = 0; w.w = -1;
        if (idx < k1) {
            rc = rb[idx]; mv = mb[idx];
            float sigt = 1.0f / rc.y, sigr = 1.0f / rc.w;
            w.x = max((int)floorf((rc.x - WSIG * sigt - THETA_MIN) / T_BIN - 0.5f), 0);
            w.y = min((int)ceilf((rc.x + WSIG * sigt - THETA_MIN) / T_BIN + 0.5f), TBINS - 1);
            w.z = max((int)floorf((rc.z - WSIG * sigr - R_MIN) / R_BIN - 0.5f) - c0, 0);
            w.w = min((int)ceilf((rc.z + WSIG * sigr - R_MIN) / R_BIN + 0.5f) - c0, nbmax);
        }
        prec[0][tid] = rc; pmv[0][tid] = mv; pwin[0][tid] = w;
    }

    int parity = 0;
    for (int ks = k0; ks < k1; ks += 32, parity ^= 1) {
        __syncthreads();
        if (tid < 32) {
            // prefetch next chunk while others fill edges
            if (ks + 32 < k1) {
                int idx = ks + 32 + tid;
                float4 rc; rc.x = 0.f; rc.y = 0.f; rc.z = 0.f; rc.w = 0.f;
                float mv = 0.f;
                int4 w; w.x = 0; w.y = -1; w.z = 0; w.w = -1;
                if (idx < k1) {
                    rc = rb[idx]; mv = mb[idx];
                    float sigt = 1.0f / rc.y, sigr = 1.0f / rc.w;
                    w.x = max((int)floorf((rc.x - WSIG * sigt - THETA_MIN) / T_BIN - 0.5f), 0);
                    w.y = min((int)ceilf((rc.x + WSIG * sigt - THETA_MIN) / T_BIN + 0.5f), TBINS - 1);
                    w.z = max((int)floorf((rc.z - WSIG * sigr - R_MIN) / R_BIN - 0.5f) - c0, 0);
                    w.w = min((int)ceilf((rc.z + WSIG * sigr - R_MIN) / R_BIN + 0.5f) - c0, nbmax);
                }
                prec[parity ^ 1][tid] = rc; pmv[parity ^ 1][tid] = mv;
                pwin[parity ^ 1][tid] = w;
            }
        } else {
            // windowed edge fill: 15 threads per pixel, {0, erfcf, 1} one-pass
            int j = tid - 32;
            int pix = j / 15, tsub = j - pix * 15;
            float4 rc = prec[parity][pix];
            int4  w  = pwin[parity][pix];
            for (int e = tsub; e < NET; e += 15) {
                if (e < NEA) {
                    float v;
                    if (e < w.x) v = 0.0f;
                    else if (e > w.y + 1) v = 1.0f;
                    else {
                        float edge = THETA_MIN + ((float)e - 0.5f) * T_BIN;
                        v = phi_cdf((edge - rc.x) * rc.y);
                    }
                    EA[e * EST + pix] = v;
                } else {
                    int n = e - NEA;
                    float v;
                    if (n < w.z) v = 0.0f;
                    else if (n > w.w + 1) v = 1.0f;
                    else {
                        float edge = R_MIN + ((float)(c0 + n) - 0.5f) * R_BIN;
                        v = phi_cdf((edge - rc.z) * rc.w);
                    }
                    EB[n * EST + pix] = v;
                }
            }
        }
        __syncthreads();

        // dense diff + bf16 hi/lo split (conflict-free mapping, R8-verified)
        {
            int pix = tid & 31, srow = tid >> 5;
            #pragma unroll
            for (int i = 0; i < 16; ++i) {
                int slot = srow + 16 * i;
                if (slot < MPAD) {
                    float wt = (EA[(slot + 1) * EST + pix] - EA[slot * EST + pix])
                             * pmv[parity][pix];
                    unsigned short hb = f2bf(wt);
                    Ah[slot * 32 + pix] = hb;
                    Al[slot * 32 + pix] = f2bf(wt - bf2f(hb));
                } else {
                    int n = slot - MPAD;
                    float wr = EB[(n + 1) * EST + pix] - EB[n * EST + pix];
                    unsigned short hb = f2bf(wr);
                    Bh[n * 32 + pix] = hb;
                    Bl[n * 32 + pix] = f2bf(wr - bf2f(hb));
                }
            }
        }
        __syncthreads();

        int kq = (lane >> 4) * 8;
        int mr = lane & 15;
        v8s bh = *((__shared__ v8s*)&Bh[(nsub * 16 + mr) * 32 + kq]);
        v8s bl = *((__shared__ v8s*)&Bl[(nsub * 16 + mr) * 32 + kq]);
        #pragma unroll
        for (int mt = 0; mt < 6; ++mt) {
            int mbase = (mhalf * 6 + mt) * 16;
            v8s ah = *((__shared__ v8s*)&Ah[(mbase + mr) * 32 + kq]);
            v8s al = *((__shared__ v8s*)&Al[(mbase + mr) * 32 + kq]);
            acc[mt] = __builtin_amdgcn_mfma_f32_16x16x32_bf16(ah, bh, acc[mt], 0, 0, 0);
            acc[mt] = __builtin_amdgcn_mfma_f32_16x16x32_bf16(ah, bl, acc[mt], 0, 0, 0);
            acc[mt] = __builtin_amdgcn_mfma_f32_16x16x32_bf16(al, bh, acc[mt], 0, 0, 0);
        }
    }

    // drain: plain stores to private slab (unconditional -> zero slabs for
    // empty/idle blocks, required by reduce)
    float* slab = slabs + (size_t)blockIdx.x * TCELL;
    int colt = nsub * 16 + (lane & 15);
    int rq = (lane >> 4) * 4;
    #pragma unroll
    for (int mt = 0; mt < 6; ++mt) {
        int rbase = (mhalf * 6 + mt) * 16 + rq;
        #pragma unroll
        for (int r = 0; r < 4; ++r) {
            int row = rbase + r;
            if (row < TBINS) slab[row * 64 + colt] = acc[mt][r];
        }
    }
}

// Sum KB partial slabs per tile; each out cell written exactly once.
__global__ void reduce_kernel(const float* __restrict__ slabs,
                              float* __restrict__ out) {
    int i = blockIdx.x * blockDim.x + threadIdx.x;
    if (i >= NT * TCELL) return;
    int tile = i / TCELL, cell = i - tile * TCELL;
    int row = cell >> 6, colt = cell & 63;
    int gcol = tile * 64 + colt;
    if (gcol >= RBINS) return;
    const float* base = slabs + (size_t)tile * TCELL + cell;
    float s0 = 0.f, s1 = 0.f, s2 = 0.f, s3 = 0.f;
    #pragma unroll 4
    for (int kb = 0; kb < KB; kb += 4) {
        s0 += base[(size_t)(kb + 0) * NT * TCELL];
        s1 += base[(size_t)(kb + 1) * NT * TCELL];
        s2 += base[(size_t)(kb + 2) * NT * TCELL];
        s3 += base[(size_t)(kb + 3) * NT * TCELL];
    }
    out[row * RBINS + gcol] = (s0 + s1) + (s2 + s3);
}

extern "C" void kernel_launch(void* const* d_in, const int* in_sizes, int n_in,
                              void* d_out, int out_size, void* d_ws, size_t ws_size,
                              hipStream_t stream) {
    const float* img  = (const float*)d_in[0];
    const float* mask = (const float*)d_in[1];
    float* out = (float*)d_out;

    // ws: counts @0 (1 KB) ; recs @1024 (3.15 MB) ; mvs (786 KB) ;
    // slabs @3933184 (480*45 KB = 22.1 MB)
    char* ws = (char*)d_ws;
    int*    counts = (int*)ws;
    float4* recs   = (float4*)(ws + 1024);
    float*  mvs    = (float*)(ws + 1024 + (size_t)NT * BCAP * 16);
    float*  slabs  = (float*)(ws + 1024 + (size_t)NT * BCAP * 20);

    hipMemsetAsync(counts, 0, NT * PADC * sizeof(int), stream);
    prep_kernel<<<NPIX / 256, 256, 0, stream>>>(img, mask, counts, recs, mvs);
    gemm_kernel<<<NT * KB, 512, 0, stream>>>(recs, mvs, counts, slabs);
    reduce_kernel<<<(NT * TCELL + 255) / 256, 256, 0, stream>>>(slabs, out);
}

// Round 10
// 99.191 us; speedup vs baseline: 1.0765x; 1.0005x over previous
//
#include <hip/hip_runtime.h>
#include <math.h>

#define H 512
#define W 512
#define TBINS 180
#define RBINS 360
#define NPIX (H*W)
#define NCELL (TBINS*RBINS)

#define THETA_MIN (-1.5707963267948966f)
#define T_BIN ((float)(3.141592653589793 / 179.0))
#define R_MIN (-724.0773439350246f)
#define R_BIN ((float)(2.0 * 724.0773439350246 / 359.0))
#define THR_VAR 100.0f
#define WSIG 6.0f          // window: tail mass < 2e-9, << 1.16e-2 budget (stable R4-R9)

#define NT 6               // rho tiles (64 cols each)
#define KB 80              // k-blocks per tile -> 480 gemm blocks
#define BCAP 32768
#define MPAD 192           // theta rows padded to 12 m-tiles of 16
#define PADC 32            // counts padded 128 B apart

#define NEA 193            // theta edges
#define NEB 65             // rho edges
#define NET (NEA + NEB)    // 258 combined
#define EST 33             // edge-row stride (conflict-free)

typedef short v8s __attribute__((ext_vector_type(8)));
typedef float v4f __attribute__((ext_vector_type(4)));

__device__ __forceinline__ float phi_cdf(float z) {
    return 0.5f * erfcf(-0.70710678118654752f * z);
}
__device__ __forceinline__ unsigned short f2bf(float f) {   // RNE f32->bf16
    unsigned u = __float_as_uint(f);
    return (unsigned short)((u + 0x7FFF + ((u >> 16) & 1)) >> 16);
}
__device__ __forceinline__ float bf2f(unsigned short b) {
    return __uint_as_float(((unsigned)b) << 16);
}

struct PixParams { float theta, rho, var_theta, var_rho; };

// Faithful to reference incl. row_s quirk (residual uses img[clip(hi+dx), wi]).
__device__ __forceinline__ PixParams compute_pixel(const float* __restrict__ img,
                                                   int hi, int wi) {
    int xm = max(hi - 1, 0), xp = min(hi + 1, H - 1);
    int ym = max(wi - 1, 0), yp = min(wi + 1, W - 1);
    const float* r0 = img + xm * W;
    const float* r1 = img + hi * W;
    const float* r2 = img + xp * W;
    float s00 = r0[ym], s01 = r0[wi], s02 = r0[yp];
    float s10 = r1[ym], s11 = r1[wi], s12 = r1[yp];
    float s20 = r2[ym], s21 = r2[wi], s22 = r2[yp];

    float alpha_s = (s20 + s21 + s22) - (s00 + s01 + s02);
    float beta_s  = (s02 + s12 + s22) - (s00 + s10 + s20);
    float gsum    = s00 + s01 + s02 + s10 + s11 + s12 + s20 + s21 + s22;

    float alpha = alpha_s * (1.0f / 6.0f) + 1e-6f;
    float beta  = beta_s  * (1.0f / 6.0f) + 1e-6f;
    float gamma = gsum * (1.0f / 9.0f);

    float cvals[3] = { s01, s11, s21 };
    float eps2 = 0.0f;
    #pragma unroll
    for (int ix = 0; ix < 3; ++ix) {
        float dx = (float)(ix - 1);
        float c = cvals[ix];
        #pragma unroll
        for (int iy = 0; iy < 3; ++iy) {
            float dy = (float)(iy - 1);
            float r = c - alpha * dy - beta * dx - gamma;
            eps2 += r * r;
        }
    }
    float noise_var = eps2 * (1.0f / 7.0f);
    float va = noise_var * (1.0f / 6.0f);
    float g2 = alpha * alpha + beta * beta;
    float var_theta = (beta * beta * va + alpha * alpha * va) / (g2 * g2);

    float theta = atanf(beta / alpha);
    float ct = cosf(theta), st = sinf(theta);
    float x = (float)hi, y = (float)wi;
    float rho = x * ct + y * st;
    float drho = -x * st + y * ct;

    PixParams pp;
    pp.theta = theta; pp.rho = rho; pp.var_theta = var_theta;
    pp.var_rho = drho * drho * var_theta;
    return pp;
}

// Block-aggregated bucketing (wave-coalescible LDS atomics; global counter
// atomics are 1 per bucket per block on 128 B-spaced lines).
__global__ void prep_kernel(const float* __restrict__ img,
                            const float* __restrict__ mask,
                            int* __restrict__ counts,
                            float4* __restrict__ recs,
                            float* __restrict__ mvs) {
    __shared__ int lcnt[NT], gbase[NT];
    int tid = threadIdx.x;
    if (tid < NT) lcnt[tid] = 0;
    __syncthreads();

    int p = blockIdx.x * blockDim.x + tid;
    int hi = p >> 9, wi = p & (W - 1);
    float mv = mask[p];
    PixParams pp = compute_pixel(img, hi, wi);

    int myNt[2] = { -1, -1 };
    int myPos[2];
    float4 rc;
    bool valid = (pp.var_theta <= THR_VAR) && (pp.var_rho <= THR_VAR) && (mv != 0.0f);
    if (valid) {
        float sig_t = sqrtf(pp.var_theta + 1e-12f);
        float sig_r = sqrtf(pp.var_rho + 1e-12f);
        float radr = WSIG * sig_r;
        int rlo = max((int)floorf((pp.rho - radr - R_MIN) / R_BIN - 0.5f), 0);
        int rhi = min((int)ceilf((pp.rho + radr - R_MIN) / R_BIN + 0.5f), RBINS - 1);
        if (rhi >= rlo) {
            rc.x = pp.theta; rc.y = 1.0f / sig_t; rc.z = pp.rho; rc.w = 1.0f / sig_r;
            int nt0 = rlo >> 6, nt1 = rhi >> 6;   // window <= 32 bins -> <= 2 tiles
            for (int nt = nt0; nt <= nt1; ++nt) {
                int k = nt - nt0;
                myNt[k] = nt;
                myPos[k] = atomicAdd(&lcnt[nt], 1);
            }
        }
    }
    __syncthreads();
    if (tid < NT) {
        int c = lcnt[tid];
        gbase[tid] = c ? atomicAdd(&counts[tid * PADC], c) : 0;
    }
    __syncthreads();
    #pragma unroll
    for (int k = 0; k < 2; ++k) {
        if (myNt[k] >= 0) {
            int pos = gbase[myNt[k]] + myPos[k];
            if (pos < BCAP) {
                recs[myNt[k] * BCAP + pos] = rc;
                mvs[myNt[k] * BCAP + pos] = mv;
            }
        }
    }
}

// GEMM M=192(pad) N=64/tile K=bucket. Windowed erfcf edge fill (step tails),
// bf16 hi/lo split -> 3 MFMAs. Drain: v!=0-guarded device atomics straight
// into d_out (R7 measured this within ~3 us of the slab+reduce path).
__global__ void __launch_bounds__(512)
gemm_kernel(const float4* __restrict__ recs,
            const float* __restrict__ mvs,
            const int* __restrict__ counts,
            float* __restrict__ out) {
    __shared__ unsigned short Ah[MPAD * 32], Al[MPAD * 32]; // [m][k]
    __shared__ unsigned short Bh[64 * 32],  Bl[64 * 32];    // [n][k]
    __shared__ float EA[NEA * EST], EB[NEB * EST];          // edge CDFs [edge][pix]
    __shared__ float4 prec[2][32];
    __shared__ float  pmv[2][32];
    __shared__ int4   pwin[2][32];                          // tlo,thi,blo,bhi

    int nt = blockIdx.x % NT, kb = blockIdx.x / NT;
    int tid = threadIdx.x;
    int lane = tid & 63, wv = tid >> 6;
    int nsub = wv & 3, mhalf = wv >> 2;
    int c0 = nt * 64;
    int nbmax = min(63, RBINS - 1 - c0);

    int cn = min(counts[nt * PADC], BCAP);
    int chunkPix = (cn + KB - 1) / KB;
    int k0 = kb * chunkPix, k1 = min(k0 + chunkPix, cn);
    if (k0 >= k1) return;   // idle block: nothing to add (out pre-zeroed)

    v4f zero = {0.f, 0.f, 0.f, 0.f};
    v4f acc[6];
    #pragma unroll
    for (int i = 0; i < 6; ++i) acc[i] = zero;

    const float4* rb = recs + (size_t)nt * BCAP;
    const float*  mb = mvs + (size_t)nt * BCAP;

    if (tid < 32) {
        int idx = k0 + tid;
        float4 rc; rc.x = 0.f; rc.y = 0.f; rc.z = 0.f; rc.w = 0.f;
        float mv = 0.f;
        int4 w; w.x = 0; w.y = -1; w.z = 0; w.w = -1;
        if (idx < k1) {
            rc = rb[idx]; mv = mb[idx];
            float sigt = 1.0f / rc.y, sigr = 1.0f / rc.w;
            w.x = max((int)floorf((rc.x - WSIG * sigt - THETA_MIN) / T_BIN - 0.5f), 0);
            w.y = min((int)ceilf((rc.x + WSIG * sigt - THETA_MIN) / T_BIN + 0.5f), TBINS - 1);
            w.z = max((int)floorf((rc.z - WSIG * sigr - R_MIN) / R_BIN - 0.5f) - c0, 0);
            w.w = min((int)ceilf((rc.z + WSIG * sigr - R_MIN) / R_BIN + 0.5f) - c0, nbmax);
        }
        prec[0][tid] = rc; pmv[0][tid] = mv; pwin[0][tid] = w;
    }

    int parity = 0;
    for (int ks = k0; ks < k1; ks += 32, parity ^= 1) {
        __syncthreads();
        if (tid < 32) {
            if (ks + 32 < k1) {
                int idx = ks + 32 + tid;
                float4 rc; rc.x = 0.f; rc.y = 0.f; rc.z = 0.f; rc.w = 0.f;
                float mv = 0.f;
                int4 w; w.x = 0; w.y = -1; w.z = 0; w.w = -1;
                if (idx < k1) {
                    rc = rb[idx]; mv = mb[idx];
                    float sigt = 1.0f / rc.y, sigr = 1.0f / rc.w;
                    w.x = max((int)floorf((rc.x - WSIG * sigt - THETA_MIN) / T_BIN - 0.5f), 0);
                    w.y = min((int)ceilf((rc.x + WSIG * sigt - THETA_MIN) / T_BIN + 0.5f), TBINS - 1);
                    w.z = max((int)floorf((rc.z - WSIG * sigr - R_MIN) / R_BIN - 0.5f) - c0, 0);
                    w.w = min((int)ceilf((rc.z + WSIG * sigr - R_MIN) / R_BIN + 0.5f) - c0, nbmax);
                }
                prec[parity ^ 1][tid] = rc; pmv[parity ^ 1][tid] = mv;
                pwin[parity ^ 1][tid] = w;
            }
        } else {
            // windowed edge fill: 15 threads per pixel, {0, erfcf, 1} one-pass
            int j = tid - 32;
            int pix = j / 15, tsub = j - pix * 15;
            float4 rc = prec[parity][pix];
            int4  w  = pwin[parity][pix];
            for (int e = tsub; e < NET; e += 15) {
                if (e < NEA) {
                    float v;
                    if (e < w.x) v = 0.0f;
                    else if (e > w.y + 1) v = 1.0f;
                    else {
                        float edge = THETA_MIN + ((float)e - 0.5f) * T_BIN;
                        v = phi_cdf((edge - rc.x) * rc.y);
                    }
                    EA[e * EST + pix] = v;
                } else {
                    int n = e - NEA;
                    float v;
                    if (n < w.z) v = 0.0f;
                    else if (n > w.w + 1) v = 1.0f;
                    else {
                        float edge = R_MIN + ((float)(c0 + n) - 0.5f) * R_BIN;
                        v = phi_cdf((edge - rc.z) * rc.w);
                    }
                    EB[n * EST + pix] = v;
                }
            }
        }
        __syncthreads();

        // dense diff + bf16 hi/lo split (conflict-free mapping)
        {
            int pix = tid & 31, srow = tid >> 5;
            #pragma unroll
            for (int i = 0; i < 16; ++i) {
                int slot = srow + 16 * i;
                if (slot < MPAD) {
                    float wt = (EA[(slot + 1) * EST + pix] - EA[slot * EST + pix])
                             * pmv[parity][pix];
                    unsigned short hb = f2bf(wt);
                    Ah[slot * 32 + pix] = hb;
                    Al[slot * 32 + pix] = f2bf(wt - bf2f(hb));
                } else {
                    int n = slot - MPAD;
                    float wr = EB[(n + 1) * EST + pix] - EB[n * EST + pix];
                    unsigned short hb = f2bf(wr);
                    Bh[n * 32 + pix] = hb;
                    Bl[n * 32 + pix] = f2bf(wr - bf2f(hb));
                }
            }
        }
        __syncthreads();

        int kq = (lane >> 4) * 8;
        int mr = lane & 15;
        v8s bh = *((__shared__ v8s*)&Bh[(nsub * 16 + mr) * 32 + kq]);
        v8s bl = *((__shared__ v8s*)&Bl[(nsub * 16 + mr) * 32 + kq]);
        #pragma unroll
        for (int mt = 0; mt < 6; ++mt) {
            int mbase = (mhalf * 6 + mt) * 16;
            v8s ah = *((__shared__ v8s*)&Ah[(mbase + mr) * 32 + kq]);
            v8s al = *((__shared__ v8s*)&Al[(mbase + mr) * 32 + kq]);
            acc[mt] = __builtin_amdgcn_mfma_f32_16x16x32_bf16(ah, bh, acc[mt], 0, 0, 0);
            acc[mt] = __builtin_amdgcn_mfma_f32_16x16x32_bf16(ah, bl, acc[mt], 0, 0, 0);
            acc[mt] = __builtin_amdgcn_mfma_f32_16x16x32_bf16(al, bh, acc[mt], 0, 0, 0);
        }
    }

    // drain: C/D col=lane&15 (n), row=(lane>>4)*4+reg (m)  [verified R6-R9]
    int gcol = c0 + nsub * 16 + (lane & 15);
    if (gcol < RBINS) {
        int rq = (lane >> 4) * 4;
        #pragma unroll
        for (int mt = 0; mt < 6; ++mt) {
            int rbase = (mhalf * 6 + mt) * 16 + rq;
            #pragma unroll
            for (int r = 0; r < 4; ++r) {
                int row = rbase + r;
                float v = acc[mt][r];
                if (row < TBINS && v != 0.0f)
                    atomicAdd(&out[row * RBINS + gcol], v);
            }
        }
    }
}

extern "C" void kernel_launch(void* const* d_in, const int* in_sizes, int n_in,
                              void* d_out, int out_size, void* d_ws, size_t ws_size,
                              hipStream_t stream) {
    const float* img  = (const float*)d_in[0];
    const float* mask = (const float*)d_in[1];
    float* out = (float*)d_out;

    // ws: counts @0 (1 KB) ; recs @1024 (3.15 MB) ; mvs (786 KB)  (~4 MB)
    char* ws = (char*)d_ws;
    int*    counts = (int*)ws;
    float4* recs   = (float4*)(ws + 1024);
    float*  mvs    = (float*)(ws + 1024 + (size_t)NT * BCAP * 16);

    hipMemsetAsync(counts, 0, NT * PADC * sizeof(int), stream);
    hipMemsetAsync(out, 0, NCELL * sizeof(float), stream);
    prep_kernel<<<NPIX / 256, 256, 0, stream>>>(img, mask, counts, recs, mvs);
    gemm_kernel<<<NT * KB, 512, 0, stream>>>(recs, mvs, counts, out);
}

// Round 12
// 98.140 us; speedup vs baseline: 1.0880x; 1.0107x over previous
//
#include <hip/hip_runtime.h>
#include <math.h>

#define H 512
#define W 512
#define TBINS 180
#define RBINS 360
#define NPIX (H*W)
#define NCELL (TBINS*RBINS)

#define THETA_MIN (-1.5707963267948966f)
#define T_BIN ((float)(3.141592653589793 / 179.0))
#define R_MIN (-724.0773439350246f)
#define R_BIN ((float)(2.0 * 724.0773439350246 / 359.0))
#define THR_VAR 100.0f
#define WSIG 6.0f          // window: tail mass < 2e-9, << 1.16e-2 budget (stable R4-R10)

#define NT 6               // rho tiles (64 cols each)
#define KB 80              // k-blocks per tile -> 480 gemm blocks
#define BCAP 32768
#define MPAD 192           // theta rows padded to 12 m-tiles of 16
#define PADC 32            // counts padded 128 B apart

#define NEA 193            // theta edges
#define NEB 65             // rho edges
#define NET (NEA + NEB)    // 258 combined
#define EST 33             // edge-row stride (conflict-free)

typedef short v8s __attribute__((ext_vector_type(8)));
typedef float v4f __attribute__((ext_vector_type(4)));

__device__ __forceinline__ float phi_cdf(float z) {
    return 0.5f * erfcf(-0.70710678118654752f * z);
}
__device__ __forceinline__ unsigned short f2bf(float f) {   // RNE f32->bf16
    unsigned u = __float_as_uint(f);
    return (unsigned short)((u + 0x7FFF + ((u >> 16) & 1)) >> 16);
}
__device__ __forceinline__ float bf2f(unsigned short b) {
    return __uint_as_float(((unsigned)b) << 16);
}

struct PixParams { float theta, rho, var_theta, var_rho; };

// Faithful to reference incl. row_s quirk (residual uses img[clip(hi+dx), wi]).
__device__ __forceinline__ PixParams compute_pixel(const float* __restrict__ img,
                                                   int hi, int wi) {
    int xm = max(hi - 1, 0), xp = min(hi + 1, H - 1);
    int ym = max(wi - 1, 0), yp = min(wi + 1, W - 1);
    const float* r0 = img + xm * W;
    const float* r1 = img + hi * W;
    const float* r2 = img + xp * W;
    float s00 = r0[ym], s01 = r0[wi], s02 = r0[yp];
    float s10 = r1[ym], s11 = r1[wi], s12 = r1[yp];
    float s20 = r2[ym], s21 = r2[wi], s22 = r2[yp];

    float alpha_s = (s20 + s21 + s22) - (s00 + s01 + s02);
    float beta_s  = (s02 + s12 + s22) - (s00 + s10 + s20);
    float gsum    = s00 + s01 + s02 + s10 + s11 + s12 + s20 + s21 + s22;

    float alpha = alpha_s * (1.0f / 6.0f) + 1e-6f;
    float beta  = beta_s  * (1.0f / 6.0f) + 1e-6f;
    float gamma = gsum * (1.0f / 9.0f);

    float cvals[3] = { s01, s11, s21 };
    float eps2 = 0.0f;
    #pragma unroll
    for (int ix = 0; ix < 3; ++ix) {
        float dx = (float)(ix - 1);
        float c = cvals[ix];
        #pragma unroll
        for (int iy = 0; iy < 3; ++iy) {
            float dy = (float)(iy - 1);
            float r = c - alpha * dy - beta * dx - gamma;
            eps2 += r * r;
        }
    }
    float noise_var = eps2 * (1.0f / 7.0f);
    float va = noise_var * (1.0f / 6.0f);
    float g2 = alpha * alpha + beta * beta;
    float var_theta = (beta * beta * va + alpha * alpha * va) / (g2 * g2);

    float theta = atanf(beta / alpha);
    float ct = cosf(theta), st = sinf(theta);
    float x = (float)hi, y = (float)wi;
    float rho = x * ct + y * st;
    float drho = -x * st + y * ct;

    PixParams pp;
    pp.theta = theta; pp.rho = rho; pp.var_theta = var_theta;
    pp.var_rho = drho * drho * var_theta;
    return pp;
}

// Block-aggregated bucketing + folds d_out zeroing (gemm is stream-ordered
// after prep, so out is fully zeroed before any drain atomic).
__global__ void prep_kernel(const float* __restrict__ img,
                            const float* __restrict__ mask,
                            int* __restrict__ counts,
                            float4* __restrict__ recs,
                            float* __restrict__ mvs,
                            float* __restrict__ out) {
    __shared__ int lcnt[NT], gbase[NT];
    int tid = threadIdx.x;
    int gid = blockIdx.x * blockDim.x + tid;
    if (gid < NCELL) out[gid] = 0.0f;        // fused d_out zeroing
    if (tid < NT) lcnt[tid] = 0;
    __syncthreads();

    int p = gid;
    int hi = p >> 9, wi = p & (W - 1);
    float mv = mask[p];
    PixParams pp = compute_pixel(img, hi, wi);

    int myNt[2] = { -1, -1 };
    int myPos[2];
    float4 rc;
    bool valid = (pp.var_theta <= THR_VAR) && (pp.var_rho <= THR_VAR) && (mv != 0.0f);
    if (valid) {
        float sig_t = sqrtf(pp.var_theta + 1e-12f);
        float sig_r = sqrtf(pp.var_rho + 1e-12f);
        float radr = WSIG * sig_r;
        int rlo = max((int)floorf((pp.rho - radr - R_MIN) / R_BIN - 0.5f), 0);
        int rhi = min((int)ceilf((pp.rho + radr - R_MIN) / R_BIN + 0.5f), RBINS - 1);
        if (rhi >= rlo) {
            rc.x = pp.theta; rc.y = 1.0f / sig_t; rc.z = pp.rho; rc.w = 1.0f / sig_r;
            int nt0 = rlo >> 6, nt1 = rhi >> 6;   // window <= 32 bins -> <= 2 tiles
            for (int nt = nt0; nt <= nt1; ++nt) {
                int k = nt - nt0;
                myNt[k] = nt;
                myPos[k] = atomicAdd(&lcnt[nt], 1);
            }
        }
    }
    __syncthreads();
    if (tid < NT) {
        int c = lcnt[tid];
        gbase[tid] = c ? atomicAdd(&counts[tid * PADC], c) : 0;
    }
    __syncthreads();
    #pragma unroll
    for (int k = 0; k < 2; ++k) {
        if (myNt[k] >= 0) {
            int pos = gbase[myNt[k]] + myPos[k];
            if (pos < BCAP) {
                recs[myNt[k] * BCAP + pos] = rc;
                mvs[myNt[k] * BCAP + pos] = mv;
            }
        }
    }
}

// GEMM M=192(pad) N=64/tile K=bucket. Windowed erfcf edge fill (step tails),
// bf16 hi/lo split -> 3 MFMAs. Drain: v!=0-guarded device atomics into d_out.
__global__ void __launch_bounds__(512)
gemm_kernel(const float4* __restrict__ recs,
            const float* __restrict__ mvs,
            const int* __restrict__ counts,
            float* __restrict__ out) {
    __shared__ unsigned short Ah[MPAD * 32], Al[MPAD * 32]; // [m][k]
    __shared__ unsigned short Bh[64 * 32],  Bl[64 * 32];    // [n][k]
    __shared__ float EA[NEA * EST], EB[NEB * EST];          // edge CDFs [edge][pix]
    __shared__ float4 prec[2][32];
    __shared__ float  pmv[2][32];
    __shared__ int4   pwin[2][32];                          // tlo,thi,blo,bhi

    int nt = blockIdx.x % NT, kb = blockIdx.x / NT;
    int tid = threadIdx.x;
    int lane = tid & 63, wv = tid >> 6;
    int nsub = wv & 3, mhalf = wv >> 2;
    int c0 = nt * 64;
    int nbmax = min(63, RBINS - 1 - c0);

    int cn = min(counts[nt * PADC], BCAP);
    int chunkPix = (cn + KB - 1) / KB;
    int k0 = kb * chunkPix, k1 = min(k0 + chunkPix, cn);
    if (k0 >= k1) return;   // idle block: nothing to add (out pre-zeroed)

    v4f zero = {0.f, 0.f, 0.f, 0.f};
    v4f acc[6];
    #pragma unroll
    for (int i = 0; i < 6; ++i) acc[i] = zero;

    const float4* rb = recs + (size_t)nt * BCAP;
    const float*  mb = mvs + (size_t)nt * BCAP;

    if (tid < 32) {
        int idx = k0 + tid;
        float4 rc; rc.x = 0.f; rc.y = 0.f; rc.z = 0.f; rc.w = 0.f;
        float mv = 0.f;
        int4 w; w.x = 0; w.y = -1; w.z = 0; w.w = -1;
        if (idx < k1) {
            rc = rb[idx]; mv = mb[idx];
            float sigt = 1.0f / rc.y, sigr = 1.0f / rc.w;
            w.x = max((int)floorf((rc.x - WSIG * sigt - THETA_MIN) / T_BIN - 0.5f), 0);
            w.y = min((int)ceilf((rc.x + WSIG * sigt - THETA_MIN) / T_BIN + 0.5f), TBINS - 1);
            w.z = max((int)floorf((rc.z - WSIG * sigr - R_MIN) / R_BIN - 0.5f) - c0, 0);
            w.w = min((int)ceilf((rc.z + WSIG * sigr - R_MIN) / R_BIN + 0.5f) - c0, nbmax);
        }
        prec[0][tid] = rc; pmv[0][tid] = mv; pwin[0][tid] = w;
    }

    int parity = 0;
    for (int ks = k0; ks < k1; ks += 32, parity ^= 1) {
        __syncthreads();
        if (tid < 32) {
            if (ks + 32 < k1) {
                int idx = ks + 32 + tid;
                float4 rc; rc.x = 0.f; rc.y = 0.f; rc.z = 0.f; rc.w = 0.f;
                float mv = 0.f;
                int4 w; w.x = 0; w.y = -1; w.z = 0; w.w = -1;
                if (idx < k1) {
                    rc = rb[idx]; mv = mb[idx];
                    float sigt = 1.0f / rc.y, sigr = 1.0f / rc.w;
                    w.x = max((int)floorf((rc.x - WSIG * sigt - THETA_MIN) / T_BIN - 0.5f), 0);
                    w.y = min((int)ceilf((rc.x + WSIG * sigt - THETA_MIN) / T_BIN + 0.5f), TBINS - 1);
                    w.z = max((int)floorf((rc.z - WSIG * sigr - R_MIN) / R_BIN - 0.5f) - c0, 0);
                    w.w = min((int)ceilf((rc.z + WSIG * sigr - R_MIN) / R_BIN + 0.5f) - c0, nbmax);
                }
                prec[parity ^ 1][tid] = rc; pmv[parity ^ 1][tid] = mv;
                pwin[parity ^ 1][tid] = w;
            }
        } else {
            // windowed edge fill: 15 threads per pixel, {0, erfcf, 1} one-pass
            int j = tid - 32;
            int pix = j / 15, tsub = j - pix * 15;
            float4 rc = prec[parity][pix];
            int4  w  = pwin[parity][pix];
            for (int e = tsub; e < NET; e += 15) {
                if (e < NEA) {
                    float v;
                    if (e < w.x) v = 0.0f;
                    else if (e > w.y + 1) v = 1.0f;
                    else {
                        float edge = THETA_MIN + ((float)e - 0.5f) * T_BIN;
                        v = phi_cdf((edge - rc.x) * rc.y);
                    }
                    EA[e * EST + pix] = v;
                } else {
                    int n = e - NEA;
                    float v;
                    if (n < w.z) v = 0.0f;
                    else if (n > w.w + 1) v = 1.0f;
                    else {
                        float edge = R_MIN + ((float)(c0 + n) - 0.5f) * R_BIN;
                        v = phi_cdf((edge - rc.z) * rc.w);
                    }
                    EB[n * EST + pix] = v;
                }
            }
        }
        __syncthreads();

        // dense diff + bf16 hi/lo split (conflict-free mapping)
        {
            int pix = tid & 31, srow = tid >> 5;
            #pragma unroll
            for (int i = 0; i < 16; ++i) {
                int slot = srow + 16 * i;
                if (slot < MPAD) {
                    float wt = (EA[(slot + 1) * EST + pix] - EA[slot * EST + pix])
                             * pmv[parity][pix];
                    unsigned short hb = f2bf(wt);
                    Ah[slot * 32 + pix] = hb;
                    Al[slot * 32 + pix] = f2bf(wt - bf2f(hb));
                } else {
                    int n = slot - MPAD;
                    float wr = EB[(n + 1) * EST + pix] - EB[n * EST + pix];
                    unsigned short hb = f2bf(wr);
                    Bh[n * 32 + pix] = hb;
                    Bl[n * 32 + pix] = f2bf(wr - bf2f(hb));
                }
            }
        }
        __syncthreads();

        int kq = (lane >> 4) * 8;
        int mr = lane & 15;
        v8s bh = *((__shared__ v8s*)&Bh[(nsub * 16 + mr) * 32 + kq]);
        v8s bl = *((__shared__ v8s*)&Bl[(nsub * 16 + mr) * 32 + kq]);
        #pragma unroll
        for (int mt = 0; mt < 6; ++mt) {
            int mbase = (mhalf * 6 + mt) * 16;
            v8s ah = *((__shared__ v8s*)&Ah[(mbase + mr) * 32 + kq]);
            v8s al = *((__shared__ v8s*)&Al[(mbase + mr) * 32 + kq]);
            acc[mt] = __builtin_amdgcn_mfma_f32_16x16x32_bf16(ah, bh, acc[mt], 0, 0, 0);
            acc[mt] = __builtin_amdgcn_mfma_f32_16x16x32_bf16(ah, bl, acc[mt], 0, 0, 0);
            acc[mt] = __builtin_amdgcn_mfma_f32_16x16x32_bf16(al, bh, acc[mt], 0, 0, 0);
        }
    }

    // drain: C/D col=lane&15 (n), row=(lane>>4)*4+reg (m)  [verified R6-R10]
    int gcol = c0 + nsub * 16 + (lane & 15);
    if (gcol < RBINS) {
        int rq = (lane >> 4) * 4;
        #pragma unroll
        for (int mt = 0; mt < 6; ++mt) {
            int rbase = (mhalf * 6 + mt) * 16 + rq;
            #pragma unroll
            for (int r = 0; r < 4; ++r) {
                int row = rbase + r;
                float v = acc[mt][r];
                if (row < TBINS && v != 0.0f)
                    atomicAdd(&out[row * RBINS + gcol], v);
            }
        }
    }
}

extern "C" void kernel_launch(void* const* d_in, const int* in_sizes, int n_in,
                              void* d_out, int out_size, void* d_ws, size_t ws_size,
                              hipStream_t stream) {
    const float* img  = (const float*)d_in[0];
    const float* mask = (const float*)d_in[1];
    float* out = (float*)d_out;

    // ws: counts @0 (1 KB) ; recs @1024 (3.15 MB) ; mvs (786 KB)  (~4 MB)
    char* ws = (char*)d_ws;
    int*    counts = (int*)ws;
    float4* recs   = (float4*)(ws + 1024);
    float*  mvs    = (float*)(ws + 1024 + (size_t)NT * BCAP * 16);

    hipMemsetAsync(counts, 0, NT * PADC * sizeof(int), stream);
    prep_kernel<<<NPIX / 256, 256, 0, stream>>>(img, mask, counts, recs, mvs, out);
    gemm_kernel<<<NT * KB, 512, 0, stream>>>(recs, mvs, counts, out);
}